// Round 20
// baseline (304.755 us; speedup 1.0000x reference)
//
#include <hip/hip_runtime.h>
#include <hip/hip_fp8.h>
#include <cfloat>

// BruteForce top-K: B=512 x N=500000, D=128 fp32, K=100.
// (1) cvt8: copy-like grid-stride kernel converts candidates fp32->fp8 e4m3
//     into ws (256MB read + 64MB write at streaming BW).
// (2) filter8: fp8 MFMA (16x16x32_fp8_fp8) scoring; queries resident in LDS
//     as fp8 fragments (64KB, stride-1 conflict-free ds_read_b128); 32-cand
//     slices in REGISTERS (16 VGPR each, ping-pong double-buffered, no
//     barriers in main loop). A/B share identical byte->k packing so any HW
//     lane-permutation cancels. Filter t_q = 3.15*|q| (~408 survivors/query;
//     fp8 score noise sigma~0.48 << 6-sigma margin to the top-100 boundary).
// (3) fallback (only if cnt<K or cnt>cap): exact fp32 rescan, top-min(cap,256).
// (4) select: numpy-bit-exact fp32 re-score of survivors (SSE-baseline
//     emulation), rank by (value desc, id asc). Exact output.

#define D_DIM 128
#define K_TOP 100
#define THRESH_SIGMA 3.15f
#define CAP_MAX 768
#define SORTN 1024
#define KEEP_MAXF 256
#define FBLK 256          // filter blocks (1024 thr each)

typedef float f32x4 __attribute__((ext_vector_type(4)));
typedef long long i64;

template <bool W>
__device__ __forceinline__ unsigned cvtpk8(float s0, float s1, unsigned old) {
#if __has_builtin(__builtin_amdgcn_cvt_pk_fp8_f32)
    return (unsigned)__builtin_amdgcn_cvt_pk_fp8_f32(s0, s1, (int)old, W);
#else
    __hip_fp8_e4m3 a(s0), b(s1);
    unsigned pk = (unsigned)a.__x | ((unsigned)b.__x << 8);
    return W ? ((old & 0x0000FFFFu) | (pk << 16)) : ((old & 0xFFFF0000u) | pk);
#endif
}

__device__ __forceinline__ i64 mk64(unsigned lo, unsigned hi) {
    return (i64)(((unsigned long long)hi << 32) | lo);
}

__device__ __forceinline__ unsigned long long make_key(float v, unsigned id) {
    unsigned vb = __float_as_uint(v);
    unsigned vm = (vb & 0x80000000u) ? ~vb : (vb | 0x80000000u);  // monotone map
    return ((unsigned long long)vm << 32) | (0xFFFFFFFFu - id);   // val asc; id asc on tie
}

template <int S>
__device__ inline void bitonic_sort_u64(unsigned long long* buf) {
    for (int k = 2; k <= S; k <<= 1) {
        for (int j = k >> 1; j > 0; j >>= 1) {
            __syncthreads();
            for (int i = threadIdx.x; i < S; i += blockDim.x) {
                int l = i ^ j;
                if (l > i) {
                    unsigned long long a = buf[i], b = buf[l];
                    bool sw = ((i & k) == 0) ? (a > b) : (a < b);
                    if (sw) { buf[i] = b; buf[l] = a; }
                }
            }
        }
    }
    __syncthreads();
}

// threshold + counter zero
__global__ void prep2_kernel(const float* __restrict__ Qm, float* __restrict__ thr,
                             int* __restrict__ cnt, int B) {
    int b = blockIdx.x * blockDim.x + threadIdx.x;
    if (b >= B) return;
    float s = 0.f;
    for (int d = 0; d < D_DIM; ++d) { float v = Qm[(size_t)b * D_DIM + d]; s = fmaf(v, v, s); }
    thr[b] = THRESH_SIGMA * sqrtf(s);
    cnt[b] = 0;
}

// candidates fp32 -> fp8 e4m3, copy-like streaming (8 floats/thread/iter)
__global__ void cvt8_kernel(const float* __restrict__ src, uint2* __restrict__ dst,
                            long long n8) {
    long long i = (long long)blockIdx.x * blockDim.x + threadIdx.x;
    long long stride = (long long)gridDim.x * blockDim.x;
    for (; i < n8; i += stride) {
        const float4* s4 = reinterpret_cast<const float4*>(src + i * 8);
        float4 a = s4[0], b = s4[1];
        unsigned w0 = 0, w1 = 0;
        w0 = cvtpk8<false>(a.x, a.y, w0); w0 = cvtpk8<true>(a.z, a.w, w0);
        w1 = cvtpk8<false>(b.x, b.y, w1); w1 = cvtpk8<true>(b.z, b.w, w1);
        dst[i] = make_uint2(w0, w1);
    }
}

// query fp8 fragments: out[g][qb][ks2][lane] = uint4 {ks=2ks2 (8B) | ks=2ks2+1 (8B)}
// frag bytes j=0..7: fp8(Q[qrow][ks*32 + (lane>>4)*8 + j]), qrow = g*512+qb*16+(lane&15)
__global__ void qfrag8_kernel(const float* __restrict__ Qm, uint4* __restrict__ qf,
                              int B, int ngrp) {
    int tid = blockIdx.x * blockDim.x + threadIdx.x;
    int total = ngrp * 4096;
    if (tid >= total) return;
    int l   = tid & 63;
    int ks2 = (tid >> 6) & 1;
    int qb  = (tid >> 7) & 31;
    int g   = tid >> 12;
    int qrow = g * 512 + qb * 16 + (l & 15);
    int lk = (l >> 4);
    unsigned w[4] = {0u, 0u, 0u, 0u};
    if (qrow < B) {
        const float* src = Qm + (size_t)qrow * D_DIM;
#pragma unroll
        for (int h = 0; h < 2; ++h) {
            int k0 = (2 * ks2 + h) * 32 + lk * 8;
            unsigned lo = 0, hi = 0;
            lo = cvtpk8<false>(src[k0 + 0], src[k0 + 1], lo);
            lo = cvtpk8<true>(src[k0 + 2], src[k0 + 3], lo);
            hi = cvtpk8<false>(src[k0 + 4], src[k0 + 5], hi);
            hi = cvtpk8<true>(src[k0 + 6], src[k0 + 7], hi);
            w[2 * h] = lo; w[2 * h + 1] = hi;
        }
    }
    qf[(size_t)g * 4096 + qb * 128 + ks2 * 64 + l] = make_uint4(w[0], w[1], w[2], w[3]);
}

// fp8 MFMA filter: queries in LDS, 32-cand slices in regs, ping-pong pipeline.
__global__ __launch_bounds__(1024, 4) void filter8_kernel(
    const unsigned char* __restrict__ cand8, const uint4* __restrict__ qf8,
    const float* __restrict__ thr, unsigned* __restrict__ idbuf,
    int* __restrict__ cnt, int N, int Bg, int cap, int nqb,
    int nslices, int totw) {
    __shared__ __align__(16) uint4 ql[4096];   // 64 KB query fragments
    __shared__ float tl[512];
    const int t = threadIdx.x;
    const int l = t & 63;
    const int gw = blockIdx.x * (blockDim.x >> 6) + (t >> 6);
    const int lr = l & 15;
    const int lk = l >> 4;

    for (int i = t; i < nqb * 128; i += blockDim.x) ql[i] = qf8[i];
    for (int i = t; i < 512; i += blockDim.x) tl[i] = (i < Bg) ? thr[i] : 3.0e38f;
    __syncthreads();   // the only barrier

    uint2 afA[2][4], afB[2][4];

#define LOADAF(AF, S)                                                           \
    do {                                                                        \
        int c0_ = (S) * 32;                                                     \
        _Pragma("unroll")                                                       \
        for (int cb = 0; cb < 2; ++cb) {                                        \
            int gr = c0_ + cb * 16 + lr; if (gr > N - 1) gr = N - 1;            \
            const unsigned char* sp = cand8 + (size_t)gr * 128 + lk * 8;        \
            _Pragma("unroll")                                                   \
            for (int ks = 0; ks < 4; ++ks)                                      \
                AF[cb][ks] = *reinterpret_cast<const uint2*>(sp + ks * 32);     \
        }                                                                       \
    } while (0)

#define COMPUTE(AF, S)                                                          \
    do {                                                                        \
        int c0_ = (S) * 32;                                                     \
        i64 a00 = mk64(AF[0][0].x, AF[0][0].y), a01 = mk64(AF[0][1].x, AF[0][1].y); \
        i64 a02 = mk64(AF[0][2].x, AF[0][2].y), a03 = mk64(AF[0][3].x, AF[0][3].y); \
        i64 a10 = mk64(AF[1][0].x, AF[1][0].y), a11 = mk64(AF[1][1].x, AF[1][1].y); \
        i64 a12 = mk64(AF[1][2].x, AF[1][2].y), a13 = mk64(AF[1][3].x, AF[1][3].y); \
        _Pragma("unroll 1")                                                     \
        for (int qb = 0; qb < nqb; ++qb) {                                      \
            uint4 q0 = ql[qb * 128 + l];                                        \
            uint4 q1 = ql[qb * 128 + 64 + l];                                   \
            i64 b0 = mk64(q0.x, q0.y), b1 = mk64(q0.z, q0.w);                   \
            i64 b2 = mk64(q1.x, q1.y), b3 = mk64(q1.z, q1.w);                   \
            f32x4 ac0 = (f32x4){0.f, 0.f, 0.f, 0.f};                            \
            f32x4 ac1 = (f32x4){0.f, 0.f, 0.f, 0.f};                            \
            ac0 = __builtin_amdgcn_mfma_f32_16x16x32_fp8_fp8(a00, b0, ac0, 0, 0, 0); \
            ac1 = __builtin_amdgcn_mfma_f32_16x16x32_fp8_fp8(a10, b0, ac1, 0, 0, 0); \
            ac0 = __builtin_amdgcn_mfma_f32_16x16x32_fp8_fp8(a01, b1, ac0, 0, 0, 0); \
            ac1 = __builtin_amdgcn_mfma_f32_16x16x32_fp8_fp8(a11, b1, ac1, 0, 0, 0); \
            ac0 = __builtin_amdgcn_mfma_f32_16x16x32_fp8_fp8(a02, b2, ac0, 0, 0, 0); \
            ac1 = __builtin_amdgcn_mfma_f32_16x16x32_fp8_fp8(a12, b2, ac1, 0, 0, 0); \
            ac0 = __builtin_amdgcn_mfma_f32_16x16x32_fp8_fp8(a03, b3, ac0, 0, 0, 0); \
            ac1 = __builtin_amdgcn_mfma_f32_16x16x32_fp8_fp8(a13, b3, ac1, 0, 0, 0); \
            float tv = tl[qb * 16 + lr];                                        \
            float m0 = fmaxf(fmaxf(ac0[0], ac0[1]), fmaxf(ac0[2], ac0[3]));     \
            float m1 = fmaxf(fmaxf(ac1[0], ac1[1]), fmaxf(ac1[2], ac1[3]));     \
            if (fmaxf(m0, m1) > tv) {                                           \
                int qg = qb * 16 + lr;                                          \
                _Pragma("unroll")                                               \
                for (int rr = 0; rr < 4; ++rr) {                                \
                    if (ac0[rr] > tv) {                                         \
                        int cid = c0_ + (lk << 2) + rr;                         \
                        if (cid < N) {                                          \
                            int pos = atomicAdd(&cnt[qg], 1);                   \
                            if (pos < cap) idbuf[(size_t)qg * cap + pos] = (unsigned)cid; \
                        }                                                       \
                    }                                                           \
                    if (ac1[rr] > tv) {                                         \
                        int cid = c0_ + 16 + (lk << 2) + rr;                    \
                        if (cid < N) {                                          \
                            int pos = atomicAdd(&cnt[qg], 1);                   \
                            if (pos < cap) idbuf[(size_t)qg * cap + pos] = (unsigned)cid; \
                        }                                                       \
                    }                                                           \
                }                                                               \
            }                                                                   \
        }                                                                       \
    } while (0)

    int s = gw;
    if (s < nslices) {
        LOADAF(afA, s);
        int sB = s + totw;
        while (true) {
            if (sB < nslices) LOADAF(afB, sB);
            COMPUTE(afA, s);
            if (sB >= nslices) break;
            s = sB + totw;
            if (s < nslices) LOADAF(afA, s);
            COMPUTE(afB, sB);
            if (s >= nslices) break;
            sB = s + totw;
        }
    }
#undef LOADAF
#undef COMPUTE
}

// exact fallback: keeps top-keep (keep = min(cap,256)) by fp32
__global__ void fallback_kernel(const float* __restrict__ Qm, const float* __restrict__ cand,
                                unsigned* __restrict__ idbuf, int* __restrict__ cnt,
                                int N, int cap) {
    int q = blockIdx.x;
    int c0 = cnt[q];
    if (c0 >= K_TOP && c0 <= cap) return;
    int keep = (cap < KEEP_MAXF) ? cap : KEEP_MAXF;

    __shared__ unsigned long long buf[2048];
    __shared__ float qrow[D_DIM];
    __shared__ int bn;
    __shared__ float theta;
    __shared__ int validn;
    for (int i = threadIdx.x; i < D_DIM; i += blockDim.x) qrow[i] = Qm[(size_t)q * D_DIM + i];
    for (int i = threadIdx.x; i < 2048; i += blockDim.x) buf[i] = 0ULL;
    if (threadIdx.x == 0) { bn = 0; theta = -3.0e38f; }
    __syncthreads();

    for (int base = 0; base < N; base += blockDim.x) {
        int c = base + threadIdx.x;
        if (c < N) {
            float s = 0.f;
            for (int d = 0; d < D_DIM; ++d) s = fmaf(qrow[d], cand[(size_t)c * D_DIM + d], s);
            if (s > theta) {
                int p = atomicAdd(&bn, 1);
                if (p < 2048) buf[p] = make_key(s, (unsigned)c);
            }
        }
        __syncthreads();
        if (bn > 2048 - 256 - 8) {  // compress: keep top-keep, raise theta
            bitonic_sort_u64<2048>(buf);
            unsigned long long kv = (threadIdx.x < (unsigned)keep) ? buf[2047 - threadIdx.x] : 0ULL;
            __syncthreads();
            for (int i = threadIdx.x; i < 2048; i += blockDim.x) buf[i] = 0ULL;
            __syncthreads();
            if (threadIdx.x < (unsigned)keep) buf[threadIdx.x] = kv;
            if ((int)threadIdx.x == keep - 1) {
                unsigned vm = (unsigned)(kv >> 32);
                unsigned vb = (vm & 0x80000000u) ? (vm ^ 0x80000000u) : ~vm;
                theta = __uint_as_float(vb) - 0.01f;
            }
            if (threadIdx.x == 0) bn = keep;
            __syncthreads();
        }
    }
    bitonic_sort_u64<2048>(buf);
    if (threadIdx.x == 0) validn = 0;
    __syncthreads();
    unsigned long long kv = (threadIdx.x < (unsigned)keep) ? buf[2047 - threadIdx.x] : 0ULL;
    if (kv != 0ULL) atomicAdd(&validn, 1);
    __syncthreads();
    if ((int)threadIdx.x < validn && threadIdx.x < (unsigned)keep) {
        unsigned id = 0xFFFFFFFFu - (unsigned)(kv & 0xFFFFFFFFu);
        if (id < (unsigned)N) idbuf[(size_t)q * cap + threadIdx.x] = id;
    }
    if (threadIdx.x == 0) cnt[q] = (validn < keep) ? validn : keep;
}

// --- bit-exact emulation of numpy einsum fp32 dot (SSE baseline, no FMA) ---
__device__ __forceinline__ float np_lane_chain(float q0, float b0v, float q1, float b1v,
                                               float q2, float b2v, float q3, float b3v,
                                               float acc) {
    float t = __fadd_rn(__fmul_rn(q3, b3v), acc);
    t = __fadd_rn(__fmul_rn(q2, b2v), t);
    t = __fadd_rn(__fmul_rn(q1, b1v), t);
    return __fadd_rn(__fmul_rn(q0, b0v), t);
}

__device__ __forceinline__ float np_score(const float* __restrict__ qrow,
                                          const float* __restrict__ crow) {
    float acc0 = 0.f, acc1 = 0.f, acc2 = 0.f, acc3 = 0.f;
#pragma unroll
    for (int d0 = 0; d0 < D_DIM; d0 += 16) {
        float4 b0 = *reinterpret_cast<const float4*>(crow + d0 + 0);
        float4 b1 = *reinterpret_cast<const float4*>(crow + d0 + 4);
        float4 b2 = *reinterpret_cast<const float4*>(crow + d0 + 8);
        float4 b3 = *reinterpret_cast<const float4*>(crow + d0 + 12);
        acc0 = np_lane_chain(qrow[d0 + 0], b0.x, qrow[d0 + 4], b1.x,
                             qrow[d0 + 8], b2.x, qrow[d0 + 12], b3.x, acc0);
        acc1 = np_lane_chain(qrow[d0 + 1], b0.y, qrow[d0 + 5], b1.y,
                             qrow[d0 + 9], b2.y, qrow[d0 + 13], b3.y, acc1);
        acc2 = np_lane_chain(qrow[d0 + 2], b0.z, qrow[d0 + 6], b1.z,
                             qrow[d0 + 10], b2.z, qrow[d0 + 14], b3.z, acc2);
        acc3 = np_lane_chain(qrow[d0 + 3], b0.w, qrow[d0 + 7], b1.w,
                             qrow[d0 + 11], b2.w, qrow[d0 + 15], b3.w, acc3);
    }
    return __fadd_rn(__fadd_rn(acc0, acc1), __fadd_rn(acc2, acc3));
}

// selection: numpy-exact fp32 re-score, rank by (value desc, id asc)
__global__ __launch_bounds__(256) void select_kernel(
    const float* __restrict__ Qm, const float* __restrict__ cand,
    const unsigned* __restrict__ idbuf, const int* __restrict__ cnt,
    const int* __restrict__ ident, float* __restrict__ out, int N, int B, int cap) {
    __shared__ unsigned long long skey[SORTN];
    __shared__ float qrow[D_DIM];
    int q = blockIdx.x;
    for (int i = threadIdx.x; i < D_DIM; i += blockDim.x) qrow[i] = Qm[(size_t)q * D_DIM + i];
    __syncthreads();

    int n = cnt[q]; if (n > cap) n = cap; if (n > SORTN) n = SORTN;
    for (int i = threadIdx.x; i < SORTN; i += blockDim.x) {
        unsigned long long key = 0ULL;
        if (i < n) {
            unsigned id = idbuf[(size_t)q * cap + i];
            if (id < (unsigned)N) {
                float s = np_score(qrow, cand + (size_t)id * D_DIM);
                key = make_key(s, id);
            }
        }
        skey[i] = key;
    }

    bitonic_sort_u64<SORTN>(skey);   // ascending: best at the end

    for (int t = threadIdx.x; t < K_TOP; t += blockDim.x) {
        unsigned long long key = skey[SORTN - 1 - t];
        unsigned vm = (unsigned)(key >> 32);
        unsigned vb = (vm & 0x80000000u) ? (vm ^ 0x80000000u) : ~vm;
        unsigned id = 0xFFFFFFFFu - (unsigned)(key & 0xFFFFFFFFu);
        if (id >= (unsigned)N) id = 0;  // unreachable pad guard
        out[(size_t)q * K_TOP + t] = __uint_as_float(vb);
        out[(size_t)B * K_TOP + (size_t)q * K_TOP + t] = (float)ident[id];
    }
}

extern "C" void kernel_launch(void* const* d_in, const int* in_sizes, int n_in,
                              void* d_out, int out_size, void* d_ws, size_t ws_size,
                              hipStream_t stream) {
    const float* queries = (const float*)d_in[0];
    const float* cands   = (const float*)d_in[1];
    const int*   ident   = (const int*)d_in[2];
    const int B = in_sizes[0] / D_DIM;   // 512
    const int N = in_sizes[2];           // 500000
    float* out = (float*)d_out;
    const int ngrp = (B + 511) / 512;
    const int nslices = (N + 31) / 32;

    // ws layout: cnt(2KB) | thr(2KB) | qfrag8 (ngrp*64KB) | cand8 (N*128B) | idbuf
    char* ws = (char*)d_ws;
    int*   cnt = (int*)ws;
    float* thr = (float*)(ws + 2048);
    uint4* qf8 = (uint4*)(ws + 4096);
    size_t c8_off = 4096 + (size_t)ngrp * 65536;
    c8_off = (c8_off + 255) & ~(size_t)255;
    unsigned char* cand8 = (unsigned char*)(ws + c8_off);
    size_t ids_off = c8_off + (size_t)N * 128;
    ids_off = (ids_off + 255) & ~(size_t)255;
    unsigned* idbuf = (unsigned*)(ws + ids_off);
    int cap = CAP_MAX;
    if (ws_size > ids_off) {
        size_t fit = (ws_size - ids_off) / ((size_t)B * 4);
        if (fit < (size_t)cap) cap = (int)fit;
    } else cap = 1;
    if (cap < 1) cap = 1;

    prep2_kernel<<<(B + 255) / 256, 256, 0, stream>>>(queries, thr, cnt, B);
    qfrag8_kernel<<<(ngrp * 4096 + 255) / 256, 256, 0, stream>>>(queries, qf8, B, ngrp);

    long long n8 = (long long)N * D_DIM / 8;
    cvt8_kernel<<<2048, 256, 0, stream>>>(cands, (uint2*)cand8, n8);

    int totw = FBLK * 16;
    for (int g = 0; g < ngrp; ++g) {
        int B_g = B - g * 512; if (B_g > 512) B_g = 512;
        int nqb = (B_g + 15) / 16;
        filter8_kernel<<<FBLK, 1024, 0, stream>>>(
            cand8, qf8 + (size_t)g * 4096, thr + (size_t)g * 512,
            idbuf + (size_t)g * 512 * cap, cnt + (size_t)g * 512,
            N, B_g, cap, nqb, nslices, totw);
    }

    fallback_kernel<<<B, 256, 0, stream>>>(queries, cands, idbuf, cnt, N, cap);

    select_kernel<<<B, 256, 0, stream>>>(queries, cands, idbuf, cnt, ident, out, N, B, cap);
}